// Round 7
// baseline (147.763 us; speedup 1.0000x reference)
//
#include <hip/hip_runtime.h>

// MoE router, fp32-accurate via bf16-split MFMA (verified absmax 9.8e-4).
// x = token_inputs * jitter; logits = x @ w + b; softmax E=64; top-2 mask.
// Tokens = 32768, H = 2048, E = 64.
//
// R7: latency attack. K-split 2 -> 4096 waves = 16 waves/CU (4/SIMD TLP).
// Block = 256 thr / 4 waves / 32 tokens; wave wv: tokens 16*(wv&1),
// k-half (wv>>1). Grid 1024 = exactly 4 blocks/CU.
// Staging converts x*jitter to bf16 hi/lo IN LDS, so the inner k-step is
// pure {2x ds_read_b128 + 12 MFMA} with no VALU between read and MFMA.
// Even/odd named register sets prefetch x,j 2-3 chunks ahead; sched_barrier
// pins the loads (R6's collapse: scheduler sank them, VGPR=52).
// B frags from d_ws (fragment-linear, L1-hot across waves), single set.

#define H    2048
#define E    64
#define NKS2 32              // K=32 steps per wave (k-split 2: 1024 k each)

typedef __attribute__((ext_vector_type(8))) short bf16x8;
typedef __attribute__((ext_vector_type(4))) float f32x4;

__device__ inline ushort f2bf_rne(float f) {
    union { float f; unsigned u; } c; c.f = f;
    const unsigned r = (c.u + 0x7FFFu + ((c.u >> 16) & 1u)) >> 16;
    return (ushort)r;
}
__device__ inline float bf2f(ushort h) {
    union { unsigned u; float f; } c; c.u = ((unsigned)h) << 16;
    return c.f;
}

// ---- pre-kernel: pack w into fragment-linear hi/lo bf16 (R6, unchanged) ----
// frag pair base (ks*4+n)*1024 + lane*8 ; hi at +0, lo at +512.
__global__ __launch_bounds__(256)
void wpack_kernel(const float* __restrict__ w, ushort* __restrict__ bp)
{
    const int t    = blockIdx.x * 256 + threadIdx.x;  // 0..16383
    const int lane = t & 63;
    const int n    = (t >> 6) & 3;
    const int ks   = t >> 8;                          // 0..63
    const int c    = lane & 15, g = lane >> 4;

    const float* src = w + (size_t)(ks * 32 + g * 8) * E + n * 16 + c;
    bf16x8 vh, vl;
#pragma unroll
    for (int s = 0; s < 8; ++s) {
        const float  v = src[(size_t)s * E];
        const ushort h = f2bf_rne(v);
        vh[s] = (short)h;
        vl[s] = (short)f2bf_rne(v - bf2f(h));
    }
    ushort* d = bp + ((size_t)(ks * 4 + n) * 2 * 64 + lane) * 8;
    *(bf16x8*)d         = vh;
    *(bf16x8*)(d + 512) = vl;
}

// ---- main kernel ----
__global__ __launch_bounds__(256, 4)
void router_kernel(const float* __restrict__ xg,
                   const float* __restrict__ jg,
                   const ushort* __restrict__ bp,
                   const float* __restrict__ bias,
                   float* __restrict__ out)
{
    // [wave][buf][hi/lo][tok][k] bf16 = 16 KB, wave-private (no barriers)
    __shared__ ushort stg[4][2][2][16][32];
    // k-split partial logits (padded rows: 20 words -> banks rotate)
    __shared__ float  red[2][64][20];                  // 10 KB

    const int tid  = threadIdx.x;
    const int wv   = tid >> 6;
    const int lane = tid & 63;
    const int ln   = lane & 15;          // token-in-tile / expert col
    const int g    = lane >> 4;          // k-group
    const int wtok = (wv & 1) << 4;      // 0 | 16
    const int kh   = wv >> 1;            // k half
    const size_t tokBase = (size_t)blockIdx.x * 32 + wtok;

    // staging coords: lane covers tok (lane>>2), k (lane&3)*8 .. +8
    const int stok = lane >> 2;
    const int sk8  = (lane & 3) << 3;
    const float* xb = xg + (tokBase + stok) * H + kh * 1024 + sk8;
    const float* jb = jg + (tokBase + stok) * H + kh * 1024 + sk8;
    const ushort* bpw = bp + (size_t)kh * 131072 + (size_t)lane * 8;

    f32x4 acc[4];
#pragma unroll
    for (int n = 0; n < 4; ++n) acc[n] = (f32x4){0.f, 0.f, 0.f, 0.f};

    float4 xa0, xa1, ja0, ja1;   // set A
    float4 xo0, xo1, jo0, jo1;   // set O
    bf16x8 BH[4], BL[4];

#define LOAD_XJ(X0, X1, J0, J1, c) do {                 \
        const size_t o_ = (size_t)(c) * 32;             \
        X0 = *(const float4*)(xb + o_);                 \
        X1 = *(const float4*)(xb + o_ + 4);             \
        J0 = *(const float4*)(jb + o_);                 \
        J1 = *(const float4*)(jb + o_ + 4);             \
    } while (0)

#define STAGEW(b, X0, X1, J0, J1) do {                  \
        float p_[8];                                    \
        p_[0] = X0.x * J0.x; p_[1] = X0.y * J0.y;       \
        p_[2] = X0.z * J0.z; p_[3] = X0.w * J0.w;       \
        p_[4] = X1.x * J1.x; p_[5] = X1.y * J1.y;       \
        p_[6] = X1.z * J1.z; p_[7] = X1.w * J1.w;       \
        bf16x8 vh_, vl_;                                \
        _Pragma("unroll")                               \
        for (int i_ = 0; i_ < 8; ++i_) {                \
            const ushort h_ = f2bf_rne(p_[i_]);         \
            vh_[i_] = (short)h_;                        \
            vl_[i_] = (short)f2bf_rne(p_[i_] - bf2f(h_)); \
        }                                               \
        *(bf16x8*)&stg[wv][b][0][stok][sk8] = vh_;      \
        *(bf16x8*)&stg[wv][b][1][stok][sk8] = vl_;      \
    } while (0)

#define LOAD_B(c) do {                                              \
        _Pragma("unroll")                                           \
        for (int n_ = 0; n_ < 4; ++n_) {                            \
            const ushort* p_ = bpw + (size_t)((c) * 4 + n_) * 1024; \
            BH[n_] = *(const bf16x8*)p_;                            \
            BL[n_] = *(const bf16x8*)(p_ + 512);                    \
        }                                                           \
    } while (0)

#define KSTEP(b) do {                                               \
        const bf16x8 ah_ = *(const bf16x8*)&stg[wv][b][0][ln][g * 8]; \
        const bf16x8 al_ = *(const bf16x8*)&stg[wv][b][1][ln][g * 8]; \
        _Pragma("unroll")                                           \
        for (int n_ = 0; n_ < 4; ++n_) {                            \
            acc[n_] = __builtin_amdgcn_mfma_f32_16x16x32_bf16(ah_, BH[n_], acc[n_], 0, 0, 0); \
            acc[n_] = __builtin_amdgcn_mfma_f32_16x16x32_bf16(al_, BH[n_], acc[n_], 0, 0, 0); \
            acc[n_] = __builtin_amdgcn_mfma_f32_16x16x32_bf16(ah_, BL[n_], acc[n_], 0, 0, 0); \
        }                                                           \
    } while (0)

    // ---- prologue ----
    LOAD_XJ(xa0, xa1, ja0, ja1, 0);
    LOAD_XJ(xo0, xo1, jo0, jo1, 1);
    STAGEW(0, xa0, xa1, ja0, ja1);

    // ---- main loop: hand-unrolled x2, even/odd named sets ----
#pragma unroll 1
    for (int c = 0; c < NKS2; c += 2) {
        // even half: compute chunk c (buf0)
        if (c + 2 < NKS2) LOAD_XJ(xa0, xa1, ja0, ja1, c + 2);
        __builtin_amdgcn_sched_barrier(0);
        if (c + 1 < NKS2) STAGEW(1, xo0, xo1, jo0, jo1);
        LOAD_B(c);
        KSTEP(0);
        // odd half: compute chunk c+1 (buf1)
        if (c + 3 < NKS2) LOAD_XJ(xo0, xo1, jo0, jo1, c + 3);
        __builtin_amdgcn_sched_barrier(0);
        if (c + 2 < NKS2) STAGEW(0, xa0, xa1, ja0, ja1);
        LOAD_B(c + 1);
        KSTEP(1);
    }

    // ---- k-split reduction ----
    if (kh == 1) {
        const int w2 = wv - 2;
#pragma unroll
        for (int n = 0; n < 4; ++n)
            *(f32x4*)&red[w2][lane][n << 2] = acc[n];
    }
    __syncthreads();
    if (kh == 1) return;

#pragma unroll
    for (int n = 0; n < 4; ++n)
        acc[n] += *(const f32x4*)&red[wv][lane][n << 2];

    // ---- epilogue: softmax + top-2 per token within 16-lane groups ----
    const float b0 = bias[ln], b1 = bias[16 + ln], b2 = bias[32 + ln], b3 = bias[48 + ln];
    float* outw = out + tokBase * E;

#pragma unroll
    for (int r = 0; r < 4; ++r) {
        const float v0 = acc[0][r] + b0;
        const float v1 = acc[1][r] + b1;
        const float v2 = acc[2][r] + b2;
        const float v3 = acc[3][r] + b3;

        float p1 = v0; int i1 = ln;
        float p2 = -3.0e38f; int i2 = ln;
        if (v1 > p1)      { p2 = p1; i2 = i1; p1 = v1; i1 = 16 + ln; }
        else if (v1 > p2) { p2 = v1; i2 = 16 + ln; }
        if (v2 > p1)      { p2 = p1; i2 = i1; p1 = v2; i1 = 32 + ln; }
        else if (v2 > p2) { p2 = v2; i2 = 32 + ln; }
        if (v3 > p1)      { p2 = p1; i2 = i1; p1 = v3; i1 = 48 + ln; }
        else if (v3 > p2) { p2 = v3; i2 = 48 + ln; }

#pragma unroll
        for (int m = 1; m <= 8; m <<= 1) {
            const float q1 = __shfl_xor(p1, m, 16);
            const int   k1 = __shfl_xor(i1, m, 16);
            const float q2 = __shfl_xor(p2, m, 16);
            const int   k2 = __shfl_xor(i2, m, 16);
            const bool  bw = (q1 > p1) || (q1 == p1 && k1 < i1);
            const float f1 = bw ? q1 : p1;  const int fi1 = bw ? k1 : i1;
            const float lo = bw ? p1 : q1;  const int loi = bw ? i1 : k1;
            const float sn = bw ? q2 : p2;  const int sni = bw ? k2 : i2;
            const bool  rw = (lo > sn) || (lo == sn && loi < sni);
            p2 = rw ? lo : sn;  i2 = rw ? loi : sni;
            p1 = f1;            i1 = fi1;
        }

        float d = __expf(v0 - p1) + __expf(v1 - p1) + __expf(v2 - p1) + __expf(v3 - p1);
#pragma unroll
        for (int m = 1; m <= 8; m <<= 1) d += __shfl_xor(d, m, 16);

        const float inv = 1.f / d;
        const float w2p = __expf(p2 - p1) * inv;

        const size_t trow = (size_t)(g * 4 + r) * E;
        outw[trow +      ln] = (     ln == i1) ? inv : (     ln == i2) ? w2p : 0.f;
        outw[trow + 16 + ln] = (16 + ln == i1) ? inv : (16 + ln == i2) ? w2p : 0.f;
        outw[trow + 32 + ln] = (32 + ln == i1) ? inv : (32 + ln == i2) ? w2p : 0.f;
        outw[trow + 48 + ln] = (48 + ln == i1) ? inv : (48 + ln == i2) ? w2p : 0.f;
    }
}

extern "C" void kernel_launch(void* const* d_in, const int* in_sizes, int n_in,
                              void* d_out, int out_size, void* d_ws, size_t ws_size,
                              hipStream_t stream)
{
    const float* x   = (const float*)d_in[0];
    const float* jit = (const float*)d_in[1];
    const float* w   = (const float*)d_in[2];
    const float* b   = (const float*)d_in[3];
    float*       out = (float*)d_out;

    ushort* bpack = (ushort*)d_ws;   // 512 frags x 1 KB = 512 KB

    hipLaunchKernelGGL(wpack_kernel, dim3(64), dim3(256), 0, stream, w, bpack);

    const int n_tok = in_sizes[0] / H;   // 32768
    dim3 grid(n_tok / 32), block(256);
    hipLaunchKernelGGL(router_kernel, grid, block, 0, stream,
                       x, jit, bpack, b, out);
}

// Round 8
// 138.170 us; speedup vs baseline: 1.0694x; 1.0694x over previous
//
#include <hip/hip_runtime.h>

// MoE router, fp32-accurate via bf16-split MFMA (verified absmax 9.8e-4).
// x = token_inputs * jitter; logits = x @ w + b; softmax E=64; top-2 mask.
// Tokens = 32768, H = 2048, E = 64.
//
// R8: fix vmcnt-ordering. vmcnt drains IN ORDER, so loads must be issued in
// consumption order: B(c) first (L2-hot, consumed this iter), then staging
// VALU, then the HBM prefetch xj(c+3) (consumed 2 iters later). The wait
// before KSTEP is then vmcnt(4) instead of vmcnt(0)+HBM-drain (R7's bug:
// B issued last -> every k-step waited on the fresh HBM prefetch).
// K-split 2, 16 waves/CU, bf16 hi/lo staged in wave-private LDS, no barriers
// in the main loop. B single-set (VGPR ~105 < 128 cap for 4 waves/SIMD).

#define H    2048
#define E    64
#define NKS2 32              // k-steps of 32 per wave (k-split 2)

typedef __attribute__((ext_vector_type(8))) short bf16x8;
typedef __attribute__((ext_vector_type(4))) float f32x4;

__device__ inline ushort f2bf_rne(float f) {
    union { float f; unsigned u; } c; c.f = f;
    const unsigned r = (c.u + 0x7FFFu + ((c.u >> 16) & 1u)) >> 16;
    return (ushort)r;
}
__device__ inline float bf2f(ushort h) {
    union { unsigned u; float f; } c; c.u = ((unsigned)h) << 16;
    return c.f;
}

// ---- pre-kernel: pack w into fragment-linear hi/lo bf16 (unchanged) ----
__global__ __launch_bounds__(256)
void wpack_kernel(const float* __restrict__ w, ushort* __restrict__ bp)
{
    const int t    = blockIdx.x * 256 + threadIdx.x;  // 0..16383
    const int lane = t & 63;
    const int n    = (t >> 6) & 3;
    const int ks   = t >> 8;                          // 0..63
    const int c    = lane & 15, g = lane >> 4;

    const float* src = w + (size_t)(ks * 32 + g * 8) * E + n * 16 + c;
    bf16x8 vh, vl;
#pragma unroll
    for (int s = 0; s < 8; ++s) {
        const float  v = src[(size_t)s * E];
        const ushort h = f2bf_rne(v);
        vh[s] = (short)h;
        vl[s] = (short)f2bf_rne(v - bf2f(h));
    }
    ushort* d = bp + ((size_t)(ks * 4 + n) * 2 * 64 + lane) * 8;
    *(bf16x8*)d         = vh;
    *(bf16x8*)(d + 512) = vl;
}

// ---- main kernel ----
__global__ __launch_bounds__(256, 4)
void router_kernel(const float* __restrict__ xg,
                   const float* __restrict__ jg,
                   const ushort* __restrict__ bp,
                   const float* __restrict__ bias,
                   float* __restrict__ out)
{
    // [wave][buf][hi/lo][tok][k] bf16, wave-private (no barriers): 16 KB
    __shared__ ushort stg[4][2][2][16][32];
    // k-split partial logits
    __shared__ float  red[2][64][20];                  // 10 KB

    const int tid  = threadIdx.x;
    const int wv   = tid >> 6;
    const int lane = tid & 63;
    const int ln   = lane & 15;          // token-in-tile / expert col
    const int g    = lane >> 4;          // k-group
    const int wtok = (wv & 1) << 4;      // 0 | 16
    const int kh   = wv >> 1;            // k half
    const size_t tokBase = (size_t)blockIdx.x * 32 + wtok;

    // staging coords: lane covers tok (lane>>2), k 8*(lane&3) .. +8
    const int stok = lane >> 2;
    const int sk8  = (lane & 3) << 3;
    const float* xb = xg + (tokBase + stok) * H + kh * 1024 + sk8;
    const float* jb = jg + (tokBase + stok) * H + kh * 1024 + sk8;
    const ushort* bpw = bp + (size_t)kh * 131072 + (size_t)lane * 8;

    f32x4 acc[4];
#pragma unroll
    for (int n = 0; n < 4; ++n) acc[n] = (f32x4){0.f, 0.f, 0.f, 0.f};

    float4 xa0, xa1, ja0, ja1;   // set A (even-parity chunks)
    float4 xo0, xo1, jo0, jo1;   // set O (odd-parity chunks)
    bf16x8 BH[4], BL[4];         // single-set B frags

#define LOAD_XJ(X0, X1, J0, J1, c) do {                 \
        const size_t o_ = (size_t)(c) * 32;             \
        X0 = *(const float4*)(xb + o_);                 \
        X1 = *(const float4*)(xb + o_ + 4);             \
        J0 = *(const float4*)(jb + o_);                 \
        J1 = *(const float4*)(jb + o_ + 4);             \
    } while (0)

#define STAGEW(b, X0, X1, J0, J1) do {                  \
        float p_[8];                                    \
        p_[0] = X0.x * J0.x; p_[1] = X0.y * J0.y;       \
        p_[2] = X0.z * J0.z; p_[3] = X0.w * J0.w;       \
        p_[4] = X1.x * J1.x; p_[5] = X1.y * J1.y;       \
        p_[6] = X1.z * J1.z; p_[7] = X1.w * J1.w;       \
        bf16x8 vh_, vl_;                                \
        _Pragma("unroll")                               \
        for (int i_ = 0; i_ < 8; ++i_) {                \
            const ushort h_ = f2bf_rne(p_[i_]);         \
            vh_[i_] = (short)h_;                        \
            vl_[i_] = (short)f2bf_rne(p_[i_] - bf2f(h_)); \
        }                                               \
        *(bf16x8*)&stg[wv][b][0][stok][sk8] = vh_;      \
        *(bf16x8*)&stg[wv][b][1][stok][sk8] = vl_;      \
    } while (0)

#define LOAD_B(c) do {                                              \
        _Pragma("unroll")                                           \
        for (int n_ = 0; n_ < 4; ++n_) {                            \
            const ushort* p_ = bpw + (size_t)((c) * 4 + n_) * 1024; \
            BH[n_] = *(const bf16x8*)p_;                            \
            BL[n_] = *(const bf16x8*)(p_ + 512);                    \
        }                                                           \
    } while (0)

#define KSTEP(b) do {                                               \
        const bf16x8 ah_ = *(const bf16x8*)&stg[wv][b][0][ln][g * 8]; \
        const bf16x8 al_ = *(const bf16x8*)&stg[wv][b][1][ln][g * 8]; \
        _Pragma("unroll")                                           \
        for (int n_ = 0; n_ < 4; ++n_) {                            \
            acc[n_] = __builtin_amdgcn_mfma_f32_16x16x32_bf16(ah_, BH[n_], acc[n_], 0, 0, 0); \
            acc[n_] = __builtin_amdgcn_mfma_f32_16x16x32_bf16(al_, BH[n_], acc[n_], 0, 0, 0); \
            acc[n_] = __builtin_amdgcn_mfma_f32_16x16x32_bf16(ah_, BL[n_], acc[n_], 0, 0, 0); \
        }                                                           \
    } while (0)

#define SB() __builtin_amdgcn_sched_barrier(0)

    // ---- prologue: chunks 0,1 -> regs; stage 0; load 2 into set A ----
    LOAD_XJ(xa0, xa1, ja0, ja1, 0);
    LOAD_XJ(xo0, xo1, jo0, jo1, 1);
    STAGEW(0, xa0, xa1, ja0, ja1);
    LOAD_XJ(xa0, xa1, ja0, ja1, 2);

    // ---- main loop: hand-unrolled x2; per iter (consumption order):
    //      B(c) [oldest] -> stage(c+1) -> xj(c+3) [newest] -> KSTEP(c)
#pragma unroll 1
    for (int c = 0; c < NKS2; c += 2) {
        // even half: compute chunk c (buf0)
        LOAD_B(c);
        SB();
        STAGEW(1, xo0, xo1, jo0, jo1);              // chunk c+1 -> buf1
        {
            const int cl = (c + 3 < NKS2) ? c + 3 : NKS2 - 1;
            LOAD_XJ(xo0, xo1, jo0, jo1, cl);        // chunk c+3 (odd set)
        }
        SB();
        KSTEP(0);
        // odd half: compute chunk c+1 (buf1)
        LOAD_B(c + 1);
        SB();
        STAGEW(0, xa0, xa1, ja0, ja1);              // chunk c+2 -> buf0
        {
            const int cl = (c + 4 < NKS2) ? c + 4 : NKS2 - 1;
            LOAD_XJ(xa0, xa1, ja0, ja1, cl);        // chunk c+4 (even set)
        }
        SB();
        KSTEP(1);
    }

    // ---- k-split reduction ----
    if (kh == 1) {
        const int w2 = wv - 2;
#pragma unroll
        for (int n = 0; n < 4; ++n)
            *(f32x4*)&red[w2][lane][n << 2] = acc[n];
    }
    __syncthreads();
    if (kh == 1) return;

#pragma unroll
    for (int n = 0; n < 4; ++n)
        acc[n] += *(const f32x4*)&red[wv][lane][n << 2];

    // ---- epilogue: softmax + top-2 per token within 16-lane groups ----
    const float b0 = bias[ln], b1 = bias[16 + ln], b2 = bias[32 + ln], b3 = bias[48 + ln];
    float* outw = out + tokBase * E;

#pragma unroll
    for (int r = 0; r < 4; ++r) {
        const float v0 = acc[0][r] + b0;
        const float v1 = acc[1][r] + b1;
        const float v2 = acc[2][r] + b2;
        const float v3 = acc[3][r] + b3;

        float p1 = v0; int i1 = ln;
        float p2 = -3.0e38f; int i2 = ln;
        if (v1 > p1)      { p2 = p1; i2 = i1; p1 = v1; i1 = 16 + ln; }
        else if (v1 > p2) { p2 = v1; i2 = 16 + ln; }
        if (v2 > p1)      { p2 = p1; i2 = i1; p1 = v2; i1 = 32 + ln; }
        else if (v2 > p2) { p2 = v2; i2 = 32 + ln; }
        if (v3 > p1)      { p2 = p1; i2 = i1; p1 = v3; i1 = 48 + ln; }
        else if (v3 > p2) { p2 = v3; i2 = 48 + ln; }

#pragma unroll
        for (int m = 1; m <= 8; m <<= 1) {
            const float q1 = __shfl_xor(p1, m, 16);
            const int   k1 = __shfl_xor(i1, m, 16);
            const float q2 = __shfl_xor(p2, m, 16);
            const int   k2 = __shfl_xor(i2, m, 16);
            const bool  bw = (q1 > p1) || (q1 == p1 && k1 < i1);
            const float f1 = bw ? q1 : p1;  const int fi1 = bw ? k1 : i1;
            const float lo = bw ? p1 : q1;  const int loi = bw ? i1 : k1;
            const float sn = bw ? q2 : p2;  const int sni = bw ? k2 : i2;
            const bool  rw = (lo > sn) || (lo == sn && loi < sni);
            p2 = rw ? lo : sn;  i2 = rw ? loi : sni;
            p1 = f1;            i1 = fi1;
        }

        float d = __expf(v0 - p1) + __expf(v1 - p1) + __expf(v2 - p1) + __expf(v3 - p1);
#pragma unroll
        for (int m = 1; m <= 8; m <<= 1) d += __shfl_xor(d, m, 16);

        const float inv = 1.f / d;
        const float w2p = __expf(p2 - p1) * inv;

        const size_t trow = (size_t)(g * 4 + r) * E;
        outw[trow +      ln] = (     ln == i1) ? inv : (     ln == i2) ? w2p : 0.f;
        outw[trow + 16 + ln] = (16 + ln == i1) ? inv : (16 + ln == i2) ? w2p : 0.f;
        outw[trow + 32 + ln] = (32 + ln == i1) ? inv : (32 + ln == i2) ? w2p : 0.f;
        outw[trow + 48 + ln] = (48 + ln == i1) ? inv : (48 + ln == i2) ? w2p : 0.f;
    }
}

extern "C" void kernel_launch(void* const* d_in, const int* in_sizes, int n_in,
                              void* d_out, int out_size, void* d_ws, size_t ws_size,
                              hipStream_t stream)
{
    const float* x   = (const float*)d_in[0];
    const float* jit = (const float*)d_in[1];
    const float* w   = (const float*)d_in[2];
    const float* b   = (const float*)d_in[3];
    float*       out = (float*)d_out;

    ushort* bpack = (ushort*)d_ws;   // 512 frags x 1 KB = 512 KB

    hipLaunchKernelGGL(wpack_kernel, dim3(64), dim3(256), 0, stream, w, bpack);

    const int n_tok = in_sizes[0] / H;   // 32768
    dim3 grid(n_tok / 32), block(256);
    hipLaunchKernelGGL(router_kernel, grid, block, 0, stream,
                       x, jit, bpack, b, out);
}

// Round 9
// 135.471 us; speedup vs baseline: 1.0907x; 1.0199x over previous
//
#include <hip/hip_runtime.h>

// MoE router, fp32-accurate via bf16-split MFMA (verified absmax 9.8e-4).
// x = token_inputs * jitter; logits = x @ w + b; softmax E=64; top-2 mask.
// Tokens = 32768, H = 2048, E = 64.
//
// R9: stop holding the pipeline in registers (R6/R7/R8: compiler collapsed
// it every time, VGPR=52/64/60). Use global_load_lds: in-flight state lives
// in the DMA queue + LDS, not in registers. Classic m97 2-phase loop:
//   { STAGE(next buf); COMPUTE(cur buf); barrier; }
// The barrier's vmcnt(0) drain is covered by the compute phase.
// Block = 4 waves / 32 tokens; wave = 16 tok x 32 e; grid 1024 = 4 blocks/CU
// (16 waves/CU). x,j staged RAW (f32) with per-row quad-ROTATION swizzle
// applied on the global source address (gll dest must be linear); product +
// hi/lo bf16 conversion happens at compute time (VALU is otherwise idle).
// B staged via gll from the fragment-linear pack (dest layout = lane*16B,
// exact match). Epilogue: logits via LDS overlay + 8-thread/token softmax.

#define H   2048
#define E   64
#define NKS 64               // k-steps of 32

typedef __attribute__((ext_vector_type(8))) short bf16x8;
typedef __attribute__((ext_vector_type(4))) float f32x4;

#define GBL(p)  ((const __attribute__((address_space(1))) void*)(p))
#define LDSP(p) ((__attribute__((address_space(3))) void*)(p))

__device__ inline ushort f2bf_rne(float f) {
    union { float f; unsigned u; } c; c.f = f;
    const unsigned r = (c.u + 0x7FFFu + ((c.u >> 16) & 1u)) >> 16;
    return (ushort)r;
}
__device__ inline float bf2f(ushort h) {
    union { unsigned u; float f; } c; c.u = ((unsigned)h) << 16;
    return c.f;
}

// ---- pre-kernel: pack w into fragment-linear hi/lo bf16 (unchanged, verified) ----
// hi frag of (ks,n) at bp + (ks*4+n)*1024 ushorts (+ lane*8); lo at +512.
// slot s of lane (g,c) holds w[ks*32 + g*8 + s][n*16 + c].
__global__ __launch_bounds__(256)
void wpack_kernel(const float* __restrict__ w, ushort* __restrict__ bp)
{
    const int t    = blockIdx.x * 256 + threadIdx.x;  // 0..16383
    const int lane = t & 63;
    const int n    = (t >> 6) & 3;
    const int ks   = t >> 8;                          // 0..63
    const int c    = lane & 15, g = lane >> 4;

    const float* src = w + (size_t)(ks * 32 + g * 8) * E + n * 16 + c;
    bf16x8 vh, vl;
#pragma unroll
    for (int s = 0; s < 8; ++s) {
        const float  v = src[(size_t)s * E];
        const ushort h = f2bf_rne(v);
        vh[s] = (short)h;
        vl[s] = (short)f2bf_rne(v - bf2f(h));
    }
    ushort* d = bp + ((size_t)(ks * 4 + n) * 2 * 64 + lane) * 8;
    *(bf16x8*)d         = vh;
    *(bf16x8*)(d + 512) = vl;
}

// ---- main kernel ----
__global__ __launch_bounds__(256, 4)
void router_kernel(const float* __restrict__ xg,
                   const float* __restrict__ jg,
                   const ushort* __restrict__ bp,
                   const float* __restrict__ bias,
                   float* __restrict__ out)
{
    // carve one 32 KB arena:
    //   xs: [2][32 tok][32 k] f32 (8 KB)  -- quad kq of row t stored at (kq+t)&7
    //   js: same (8 KB)
    //   bs: [2*8 frags][512] ushort (16 KB), frag f = n*2+hl, lane-linear
    //   lgx (epilogue overlay on xs/js): [32][68] f32 (8.5 KB)
    __shared__ __align__(16) unsigned char smem[32768];
    float  (*xs)[32][32] = (float (*)[32][32])(void*)smem;
    float  (*js)[32][32] = (float (*)[32][32])(void*)(smem + 8192);
    ushort (*bs)[512]    = (ushort (*)[512])(void*)(smem + 16384);

    const int tid  = threadIdx.x;
    const int wv   = tid >> 6;
    const int lane = tid & 63;
    const int ln   = lane & 15;        // MFMA col / A-supplier token row
    const int g    = lane >> 4;        // k-group
    const int mh   = wv >> 1;          // token half (0: tok 0-15, 1: 16-31)
    const int nh   = wv & 1;           // expert half (0: e 0-31, 1: 32-63)
    const size_t tokBase = (size_t)blockIdx.x * 32;

    // staging source coords (x,j): lane covers dest tok wv*8 + (lane>>3),
    // stored quad position lane&7 -> source quad kq = ((lane&7)-(lane>>3))&7
    const int srow = lane >> 3;
    const int sqd  = ((lane & 7) - srow) & 7;
    const float* xsb = xg + (tokBase + wv * 8 + srow) * (size_t)H + sqd * 4;
    const float* jsb = jg + (tokBase + wv * 8 + srow) * (size_t)H + sqd * 4;
    // B source: wave wv stages n-tile wv (hi,lo)
    const ushort* bsb = bp + (size_t)wv * 1024 + (size_t)lane * 8;

    const int t = mh * 16 + ln;        // A row this lane supplies

    f32x4 acc0 = (f32x4){0.f, 0.f, 0.f, 0.f};
    f32x4 acc1 = (f32x4){0.f, 0.f, 0.f, 0.f};

#define STAGE(b, c) do {                                                      \
        __builtin_amdgcn_global_load_lds(GBL(xsb + (size_t)(c) * 32),         \
                                         LDSP(&xs[b][wv * 8][0]), 16, 0, 0);  \
        __builtin_amdgcn_global_load_lds(GBL(jsb + (size_t)(c) * 32),         \
                                         LDSP(&js[b][wv * 8][0]), 16, 0, 0);  \
        __builtin_amdgcn_global_load_lds(GBL(bsb + (size_t)(c) * 4096),       \
                                         LDSP(&bs[(b) * 8 + wv * 2][0]), 16, 0, 0); \
        __builtin_amdgcn_global_load_lds(GBL(bsb + (size_t)(c) * 4096 + 512), \
                                         LDSP(&bs[(b) * 8 + wv * 2 + 1][0]), 16, 0, 0); \
    } while (0)

#define COMPUTE(b) do {                                                       \
        const int p0 = ((2 * g + t) & 7) << 2;                                \
        const int p1 = ((2 * g + 1 + t) & 7) << 2;                            \
        const float4 xq0 = *(const float4*)&xs[b][t][p0];                     \
        const float4 xq1 = *(const float4*)&xs[b][t][p1];                     \
        const float4 jq0 = *(const float4*)&js[b][t][p0];                     \
        const float4 jq1 = *(const float4*)&js[b][t][p1];                     \
        float pr[8];                                                          \
        pr[0] = xq0.x * jq0.x; pr[1] = xq0.y * jq0.y;                         \
        pr[2] = xq0.z * jq0.z; pr[3] = xq0.w * jq0.w;                         \
        pr[4] = xq1.x * jq1.x; pr[5] = xq1.y * jq1.y;                         \
        pr[6] = xq1.z * jq1.z; pr[7] = xq1.w * jq1.w;                         \
        bf16x8 ah, al;                                                        \
        _Pragma("unroll")                                                     \
        for (int i_ = 0; i_ < 8; ++i_) {                                      \
            const ushort h_ = f2bf_rne(pr[i_]);                               \
            ah[i_] = (short)h_;                                               \
            al[i_] = (short)f2bf_rne(pr[i_] - bf2f(h_));                      \
        }                                                                     \
        const bf16x8 BH0 = *(const bf16x8*)&bs[(b) * 8 + 4 * nh + 0][lane * 8]; \
        const bf16x8 BL0 = *(const bf16x8*)&bs[(b) * 8 + 4 * nh + 1][lane * 8]; \
        const bf16x8 BH1 = *(const bf16x8*)&bs[(b) * 8 + 4 * nh + 2][lane * 8]; \
        const bf16x8 BL1 = *(const bf16x8*)&bs[(b) * 8 + 4 * nh + 3][lane * 8]; \
        acc0 = __builtin_amdgcn_mfma_f32_16x16x32_bf16(ah, BH0, acc0, 0, 0, 0); \
        acc0 = __builtin_amdgcn_mfma_f32_16x16x32_bf16(al, BH0, acc0, 0, 0, 0); \
        acc0 = __builtin_amdgcn_mfma_f32_16x16x32_bf16(ah, BL0, acc0, 0, 0, 0); \
        acc1 = __builtin_amdgcn_mfma_f32_16x16x32_bf16(ah, BH1, acc1, 0, 0, 0); \
        acc1 = __builtin_amdgcn_mfma_f32_16x16x32_bf16(al, BH1, acc1, 0, 0, 0); \
        acc1 = __builtin_amdgcn_mfma_f32_16x16x32_bf16(ah, BL1, acc1, 0, 0, 0); \
    } while (0)

    // ---- prologue ----
    STAGE(0, 0);
    __syncthreads();

    // ---- main loop: 2-phase, unrolled x2 for compile-time buffer indices ----
#pragma unroll 1
    for (int c = 0; c < NKS; c += 2) {
        STAGE(1, c + 1);
        __builtin_amdgcn_sched_barrier(0);
        COMPUTE(0);
        __syncthreads();
        if (c + 2 < NKS) STAGE(0, c + 2);
        __builtin_amdgcn_sched_barrier(0);
        COMPUTE(1);
        __syncthreads();
    }

    // ---- exchange logits via LDS overlay (rows padded to 68 words) ----
    float (*lgx)[68] = (float (*)[68])(void*)smem;
#pragma unroll
    for (int r = 0; r < 4; ++r) {
        lgx[mh * 16 + g * 4 + r][nh * 32 + ln]      = acc0[r];
        lgx[mh * 16 + g * 4 + r][nh * 32 + 16 + ln] = acc1[r];
    }
    __syncthreads();

    // ---- softmax + top-2: 8 threads per token (R3-verified logic) ----
    const int t8 = tid >> 3;           // token 0..31
    const int q8 = tid & 7;            // expert octet
    float l[8];
    *(float4*)&l[0] = *(const float4*)&lgx[t8][q8 * 8];
    *(float4*)&l[4] = *(const float4*)&lgx[t8][q8 * 8 + 4];
    const float4 bb0 = *(const float4*)(bias + q8 * 8);
    const float4 bb1 = *(const float4*)(bias + q8 * 8 + 4);
    l[0] += bb0.x; l[1] += bb0.y; l[2] += bb0.z; l[3] += bb0.w;
    l[4] += bb1.x; l[5] += bb1.y; l[6] += bb1.z; l[7] += bb1.w;

    // local top-2 (strict '>' ascending keeps lowest index on ties)
    float p1 = l[0]; int i1 = q8 * 8;
    float p2 = -3.0e38f; int i2 = q8 * 8;
#pragma unroll
    for (int i = 1; i < 8; ++i) {
        const int e = q8 * 8 + i;
        if (l[i] > p1)      { p2 = p1; i2 = i1; p1 = l[i]; i1 = e; }
        else if (l[i] > p2) { p2 = l[i]; i2 = e; }
    }

    // butterfly merge across the token's 8 threads
#pragma unroll
    for (int m = 1; m <= 4; m <<= 1) {
        const float q1 = __shfl_xor(p1, m, 8);
        const int   k1 = __shfl_xor(i1, m, 8);
        const float q2 = __shfl_xor(p2, m, 8);
        const int   k2 = __shfl_xor(i2, m, 8);
        const bool  bw = (q1 > p1) || (q1 == p1 && k1 < i1);
        const float f1 = bw ? q1 : p1;  const int fi1 = bw ? k1 : i1;
        const float lo = bw ? p1 : q1;  const int loi = bw ? i1 : k1;
        const float sn = bw ? q2 : p2;  const int sni = bw ? k2 : i2;
        const bool  rw = (lo > sn) || (lo == sn && loi < sni);
        p2 = rw ? lo : sn;  i2 = rw ? loi : sni;
        p1 = f1;            i1 = fi1;
    }

    // softmax denominator over all 64 experts
    float d = 0.f;
#pragma unroll
    for (int i = 0; i < 8; ++i) d += __expf(l[i] - p1);
#pragma unroll
    for (int m = 1; m <= 4; m <<= 1) d += __shfl_xor(d, m, 8);

    const float inv = 1.f / d;                 // top-1 prob
    const float w2  = __expf(p2 - p1) * inv;   // top-2 prob

    float* op = out + (tokBase + t8) * (size_t)E + q8 * 8;
    float4 v0, v1;
    v0.x = (q8 * 8 + 0 == i1) ? inv : (q8 * 8 + 0 == i2) ? w2 : 0.f;
    v0.y = (q8 * 8 + 1 == i1) ? inv : (q8 * 8 + 1 == i2) ? w2 : 0.f;
    v0.z = (q8 * 8 + 2 == i1) ? inv : (q8 * 8 + 2 == i2) ? w2 : 0.f;
    v0.w = (q8 * 8 + 3 == i1) ? inv : (q8 * 8 + 3 == i2) ? w2 : 0.f;
    v1.x = (q8 * 8 + 4 == i1) ? inv : (q8 * 8 + 4 == i2) ? w2 : 0.f;
    v1.y = (q8 * 8 + 5 == i1) ? inv : (q8 * 8 + 5 == i2) ? w2 : 0.f;
    v1.z = (q8 * 8 + 6 == i1) ? inv : (q8 * 8 + 6 == i2) ? w2 : 0.f;
    v1.w = (q8 * 8 + 7 == i1) ? inv : (q8 * 8 + 7 == i2) ? w2 : 0.f;
    *(float4*)op       = v0;
    *(float4*)(op + 4) = v1;
}

extern "C" void kernel_launch(void* const* d_in, const int* in_sizes, int n_in,
                              void* d_out, int out_size, void* d_ws, size_t ws_size,
                              hipStream_t stream)
{
    const float* x   = (const float*)d_in[0];
    const float* jit = (const float*)d_in[1];
    const float* w   = (const float*)d_in[2];
    const float* b   = (const float*)d_in[3];
    float*       out = (float*)d_out;

    ushort* bpack = (ushort*)d_ws;   // 512 frags x 1 KB = 512 KB

    hipLaunchKernelGGL(wpack_kernel, dim3(64), dim3(256), 0, stream, w, bpack);

    const int n_tok = in_sizes[0] / H;   // 32768
    dim3 grid(n_tok / 32), block(256);
    hipLaunchKernelGGL(router_kernel, grid, block, 0, stream,
                       x, jit, bpack, b, out);
}